// Round 5
// baseline (36.119 us; speedup 1.0000x reference)
//
#include <hip/hip_runtime.h>
#include <hip/hip_bf16.h>
#include <math.h>

#define NB 4096
#define NC 512
#define NF 128
#define NK 256           // GEMM K = 2*F  (k<128: xn^2 . iv ; k>=128: xn . -2*mu*iv)
#define TAUc 32.0f
#define ALPHAc 0.9f

typedef __attribute__((ext_vector_type(8))) short bf16x8;
typedef __attribute__((ext_vector_type(4))) float f32x4;

// Truncation-based bf16 hi/lo split: hi = trunc16(x), lo = trunc16(x - hi).
// x - trunc16(x) is exact in fp32, so total split error ~2^-16 relative.
__device__ inline void splitbf(float x, short& hi, short& lo) {
  unsigned u = __float_as_uint(x);
  hi = (short)(u >> 16);
  float l = x - __uint_as_float(u & 0xFFFF0000u);
  lo = (short)(__float_as_uint(l) >> 16);
}

// ---------- prepB: mu_n, iv=exp(-clip(lv)); B = [iv, -2*mu_n*iv] hi/lo; t3 -------
// Also resets the fused kernel's completion counter (poison-safe, runs every call).
__global__ __launch_bounds__(128) void k_prepB(const float* __restrict__ means,
                                               const float* __restrict__ logv,
                                               ushort* __restrict__ Bh,
                                               ushort* __restrict__ Bl,
                                               float* __restrict__ t3,
                                               int* __restrict__ fincount) {
  __shared__ float p2[2];
  __shared__ float q2[2];
  if (blockIdx.x == 0 && threadIdx.x == 0) atomicExch(fincount, 0);
  int c = blockIdx.x, f = threadIdx.x;
  float mu = means[(size_t)c * NF + f];
  float lv = fminf(fmaxf(logv[(size_t)c * NF + f], 0.f), 6.f);
  float iv = __expf(-lv);
  float s = mu * mu;
  #pragma unroll
  for (int o = 1; o < 64; o <<= 1) s += __shfl_xor(s, o, 64);
  if ((f & 63) == 0) p2[f >> 6] = s;
  __syncthreads();
  float mun = mu / fmaxf(sqrtf(p2[0] + p2[1]), 1e-12f);
  short h, l;
  splitbf(iv, h, l);
  Bh[(size_t)c * NK + f] = (ushort)h;
  Bl[(size_t)c * NK + f] = (ushort)l;
  splitbf(-2.f * mun * iv, h, l);
  Bh[(size_t)c * NK + NF + f] = (ushort)h;
  Bl[(size_t)c * NK + NF + f] = (ushort)l;
  float t = mun * mun * iv;
  #pragma unroll
  for (int o = 1; o < 64; o <<= 1) t += __shfl_xor(t, o, 64);
  if ((f & 63) == 0) q2[f >> 6] = t;
  __syncthreads();
  if (f == 0) t3[c] = q2[0] + q2[1];
}

// ---------- fallback-only mask machinery (not launched when Csel==NC) ------------
__global__ __launch_bounds__(512) void k_zero(int* __restrict__ colnz) {
  colnz[threadIdx.x] = 0;
}

__global__ __launch_bounds__(256) void k_mask(const int* __restrict__ T,
                                              int* __restrict__ colnz) {
  int r0 = blockIdx.x * 16;
  int a0 = 0, a1 = 0;
  for (int r = 0; r < 16; ++r) {
    const int* row = T + (size_t)(r0 + r) * NC;
    a0 |= row[threadIdx.x];
    a1 |= row[threadIdx.x + 256];
  }
  if (a0) atomicOr(colnz + threadIdx.x, 1);
  if (a1) atomicOr(colnz + threadIdx.x + 256, 1);
}

__global__ __launch_bounds__(512) void k_scan(const int* __restrict__ colnz,
                                              int* __restrict__ pos) {
  __shared__ int s[NC];
  int t = threadIdx.x;
  int f = colnz[t] ? 1 : 0;
  s[t] = f;
  __syncthreads();
  for (int o = 1; o < NC; o <<= 1) {
    int add = (t >= o) ? s[t - o] : 0;
    __syncthreads();
    s[t] += add;
    __syncthreads();
  }
  pos[t] = s[t] - f;
}

// ---------- fused: X-normalize + split-bf16 GEMM + softmax + S + loss ------------
// grid = NB/16 = 256 blocks, 512 threads = 8 waves. Block tile: 16 rows x 512 cols.
// A (16 rows, K=256, hi+lo) built in registers from X; B from global (L2-resident).
// D lives only in LDS. Loss finalized by the last block to finish (device-scope
// atomics for cross-XCD visibility; fixed-order reduce -> deterministic).
__global__ __launch_bounds__(512) void k_fused(const float* __restrict__ X,
                                               const int* __restrict__ T,
                                               const ushort* __restrict__ Bh,
                                               const ushort* __restrict__ Bl,
                                               const float* __restrict__ t3,
                                               const int* __restrict__ colnz,
                                               const int* __restrict__ pos,
                                               float* __restrict__ out,
                                               float* __restrict__ blklog,
                                               int* __restrict__ blkcnt,
                                               int* __restrict__ fincount,
                                               int Csel, int ident) {
  // 514-word row stride: rows 4kq+i land on bank offsets {0,8,16,24} per kq ->
  // 2-way aliasing on the MFMA->LDS write (free), conflict-free softmax reads.
  __shared__ float Dls[16][514];
  __shared__ float sl16[16];
  __shared__ int sc16[16];
  __shared__ float redf[256];
  __shared__ int redi[256];
  __shared__ int lastflag;
  int tid = threadIdx.x;
  int lane = tid & 63, w = tid >> 6;
  int lr = lane & 15, kq = lane >> 4;
  int r0 = blockIdx.x * 16;
  int n0 = w * 64;

  // ---- build A fragments in registers ----
  // lane covers row (r0+lr), k-slices k = 32c + 8kq + j (j=0..7, c=0..7)
  // c<4 -> xn^2 at f=32c+8kq+j ; c>=4 -> xn at same f (f = k mod 128)
  float xv[4][8];
  float rsum = 0.f;
  const float* xrow = X + (size_t)(r0 + lr) * NF + 8 * kq;
  #pragma unroll
  for (int c = 0; c < 4; ++c) {
    float4 u0 = *(const float4*)(xrow + 32 * c);
    float4 u1 = *(const float4*)(xrow + 32 * c + 4);
    xv[c][0] = u0.x; xv[c][1] = u0.y; xv[c][2] = u0.z; xv[c][3] = u0.w;
    xv[c][4] = u1.x; xv[c][5] = u1.y; xv[c][6] = u1.z; xv[c][7] = u1.w;
    #pragma unroll
    for (int j = 0; j < 8; ++j) rsum = fmaf(xv[c][j], xv[c][j], rsum);
  }
  // lanes lr, lr+16, lr+32, lr+48 share a row
  rsum += __shfl_xor(rsum, 16, 64);
  rsum += __shfl_xor(rsum, 32, 64);
  float rn = 1.0f / fmaxf(sqrtf(rsum), 1e-12f);

  bf16x8 Afh[8], Afl[8];
  #pragma unroll
  for (int c = 0; c < 4; ++c) {
    #pragma unroll
    for (int j = 0; j < 8; ++j) {
      float xn = xv[c][j] * rn;
      short h, l;
      splitbf(xn * xn, h, l);
      Afh[c][j] = h; Afl[c][j] = l;
      splitbf(xn, h, l);
      Afh[c + 4][j] = h; Afl[c + 4][j] = l;
    }
  }

  // ---- MFMA main loop: 3-product split-bf16 over col tiles t=0..3 ----
  f32x4 acc[4] = {};
  const ushort* bhp = Bh + (size_t)(n0 + lr) * NK + 8 * kq;
  const ushort* blp = Bl + (size_t)(n0 + lr) * NK + 8 * kq;
  #pragma unroll
  for (int k8 = 0; k8 < 8; ++k8) {
    #pragma unroll
    for (int t = 0; t < 4; ++t) {
      bf16x8 bh = *(const bf16x8*)(bhp + (size_t)(16 * t) * NK + 32 * k8);
      bf16x8 bl = *(const bf16x8*)(blp + (size_t)(16 * t) * NK + 32 * k8);
      acc[t] = __builtin_amdgcn_mfma_f32_16x16x32_bf16(Afh[k8], bh, acc[t], 0, 0, 0);
      acc[t] = __builtin_amdgcn_mfma_f32_16x16x32_bf16(Afl[k8], bh, acc[t], 0, 0, 0);
      acc[t] = __builtin_amdgcn_mfma_f32_16x16x32_bf16(Afh[k8], bl, acc[t], 0, 0, 0);
    }
  }

  // ---- D tile -> LDS (add t3); C/D layout: col=lane&15, row=4*kq+i ----
  #pragma unroll
  for (int t = 0; t < 4; ++t) {
    int c = n0 + 16 * t + lr;
    float tt = t3[c];
    #pragma unroll
    for (int i = 0; i < 4; ++i) Dls[4 * kq + i][c] = acc[t][i] + tt;
  }
  __syncthreads();

  // ---- per-row softmax + S + loss terms; wave w handles rows 2w, 2w+1 ----
  #pragma unroll
  for (int rr = 0; rr < 2; ++rr) {
    int r = 2 * w + rr;
    const int* Trow = T + (size_t)(r0 + r) * NC;
    float d[8]; int tf[8];
    #pragma unroll
    for (int j = 0; j < 8; ++j) {
      d[j] = Dls[r][lane + 64 * j];
      tf[j] = Trow[lane + 64 * j];
    }
    float dmin = d[0];
    #pragma unroll
    for (int j = 1; j < 8; ++j) dmin = fminf(dmin, d[j]);
    #pragma unroll
    for (int o = 1; o < 64; o <<= 1) dmin = fminf(dmin, __shfl_xor(dmin, o, 64));
    float Z = 0.f, Ps = 0.f;
    #pragma unroll
    for (int j = 0; j < 8; ++j) {
      float p = __expf(TAUc * (dmin - d[j]));
      Z += p;
      if (tf[j]) Ps += p;
    }
    #pragma unroll
    for (int o = 1; o < 64; o <<= 1) { Z += __shfl_xor(Z, o, 64); Ps += __shfl_xor(Ps, o, 64); }
    float* srow = out + 1 + (size_t)(r0 + r) * Csel;
    if (ident) {
      #pragma unroll
      for (int j = 0; j < 8; ++j)
        srow[lane + 64 * j] = tf[j] ? 1.0f : __expf(-ALPHAc * d[j]);
    } else {
      #pragma unroll
      for (int j = 0; j < 8; ++j) {
        int c = lane + 64 * j;
        if (colnz[c]) srow[pos[c]] = tf[j] ? 1.0f : __expf(-ALPHAc * d[j]);
      }
    }
    if (lane == 0) {
      float Psum = Ps / Z;
      sl16[r] = (Psum > 0.f) ? logf(Psum) : 0.f;
      sc16[r] = (Psum > 0.f) ? 1 : 0;
    }
  }
  __syncthreads();

  // ---- publish block partial (device-scope), last block finalizes ----
  if (tid == 0) {
    float s = 0.f; int c = 0;
    #pragma unroll
    for (int r = 0; r < 16; ++r) { s += sl16[r]; c += sc16[r]; }
    atomicExch(&blklog[blockIdx.x], s);
    atomicExch(&blkcnt[blockIdx.x], c);
    __threadfence();
    int old = atomicAdd(fincount, 1);
    lastflag = (old == (int)gridDim.x - 1) ? 1 : 0;
  }
  __syncthreads();
  if (lastflag) {
    if (tid < 256) {
      // atomic-RMW reads: guaranteed coherent across XCDs (plain loads could
      // hit a stale per-XCD L2 line from a previous graph replay)
      redf[tid] = atomicAdd(&blklog[tid], 0.0f);
      redi[tid] = atomicAdd(&blkcnt[tid], 0);
    }
    __syncthreads();
    for (int o = 128; o > 0; o >>= 1) {
      if (tid < o) { redf[tid] += redf[tid + o]; redi[tid] += redi[tid + o]; }
      __syncthreads();
    }
    if (tid == 0) out[0] = -redf[0] / fmaxf((float)redi[0], 1.0f);
  }
}

extern "C" void kernel_launch(void* const* d_in, const int* in_sizes, int n_in,
                              void* d_out, int out_size, void* d_ws, size_t ws_size,
                              hipStream_t stream) {
  const float* X     = (const float*)d_in[0];
  const int*   T     = (const int*)d_in[1];
  const float* means = (const float*)d_in[2];
  const float* logv  = (const float*)d_in[3];
  float* out = (float*)d_out;
  char* ws = (char*)d_ws;

  ushort* Bh      = (ushort*)(ws);                  // 256 KB
  ushort* Bl      = (ushort*)(ws + 262144);         // 256 KB
  float*  t3      = (float*) (ws + 524288);         // 2 KB
  float*  blklog  = (float*) (ws + 526336);         // 1 KB
  int*    blkcnt  = (int*)   (ws + 527360);         // 1 KB
  int*    fincount= (int*)   (ws + 528384);         // 4 B (1 KB slot)
  int*    colnz   = (int*)   (ws + 529408);         // 2 KB
  int*    pos     = (int*)   (ws + 531456);         // 2 KB

  int Csel = (out_size - 1) / NB;
  int ident = (Csel == NC);   // Csel==NC forces all-ones mask (pos = identity)

  k_prepB<<<NC, NF, 0, stream>>>(means, logv, Bh, Bl, t3, fincount);
  if (!ident) {
    k_zero<<<1, NC, 0, stream>>>(colnz);
    k_mask<<<NB / 16, 256, 0, stream>>>(T, colnz);
    k_scan<<<1, NC, 0, stream>>>(colnz, pos);
  }
  k_fused<<<NB / 16, 512, 0, stream>>>(X, T, Bh, Bl, t3, colnz, pos,
                                       out, blklog, blkcnt, fincount, Csel, ident);
}

// Round 6
// 25.517 us; speedup vs baseline: 1.4155x; 1.4155x over previous
//
#include <hip/hip_runtime.h>
#include <hip/hip_bf16.h>
#include <math.h>

#define NB 4096
#define NC 512
#define NF 128
#define NK 256           // GEMM K = 2*F  (k<128: xn^2 . iv ; k>=128: xn . -2*mu*iv)
#define TAUc 32.0f
#define ALPHAc 0.9f

typedef __attribute__((ext_vector_type(8))) short bf16x8;
typedef __attribute__((ext_vector_type(4))) float f32x4;

// Truncation-based bf16 hi/lo split: hi = trunc16(x), lo = trunc16(x - hi).
// x - trunc16(x) is exact in fp32, so total split error ~2^-16 relative.
__device__ inline void splitbf(float x, short& hi, short& lo) {
  unsigned u = __float_as_uint(x);
  hi = (short)(u >> 16);
  float l = x - __uint_as_float(u & 0xFFFF0000u);
  lo = (short)(__float_as_uint(l) >> 16);
}

// ---------- prepB: mu_n, iv=exp(-clip(lv)); B = [iv, -2*mu_n*iv] hi/lo; t3 -------
// B is stored PRE-SWIZZLED in MFMA fragment order so the fused kernel's loads are
// wave-contiguous 1KB bursts:  elem idx = ((ct*8 + k8)*64 + lane)*8 + j
// where col = ct*16 + lr, k = 32*k8 + 8*kq + j, lane = kq*16 + lr.
__global__ __launch_bounds__(128) void k_prepB(const float* __restrict__ means,
                                               const float* __restrict__ logv,
                                               ushort* __restrict__ Bh,
                                               ushort* __restrict__ Bl,
                                               float* __restrict__ t3) {
  __shared__ float p2[2];
  __shared__ float q2[2];
  int c = blockIdx.x, f = threadIdx.x;
  float mu = means[(size_t)c * NF + f];
  float lv = fminf(fmaxf(logv[(size_t)c * NF + f], 0.f), 6.f);
  float iv = __expf(-lv);
  float s = mu * mu;
  #pragma unroll
  for (int o = 1; o < 64; o <<= 1) s += __shfl_xor(s, o, 64);
  if ((f & 63) == 0) p2[f >> 6] = s;
  __syncthreads();
  float mun = mu / fmaxf(sqrtf(p2[0] + p2[1]), 1e-12f);

  int ct = c >> 4, lr = c & 15;
  // swizzled address for this column's element at GEMM-k
  auto swadr = [&](int k) {
    return (size_t)(ct * 8 + (k >> 5)) * 512 + ((k >> 3) & 3) * 128 + lr * 8 + (k & 7);
  };
  short h, l;
  splitbf(iv, h, l);
  size_t a1 = swadr(f);
  Bh[a1] = (ushort)h; Bl[a1] = (ushort)l;
  splitbf(-2.f * mun * iv, h, l);
  size_t a2 = swadr(f + NF);
  Bh[a2] = (ushort)h; Bl[a2] = (ushort)l;

  float t = mun * mun * iv;
  #pragma unroll
  for (int o = 1; o < 64; o <<= 1) t += __shfl_xor(t, o, 64);
  if ((f & 63) == 0) q2[f >> 6] = t;
  __syncthreads();
  if (f == 0) t3[c] = q2[0] + q2[1];
}

// ---------- fallback-only mask machinery (not launched when Csel==NC) ------------
__global__ __launch_bounds__(512) void k_zero(int* __restrict__ colnz) {
  colnz[threadIdx.x] = 0;
}

__global__ __launch_bounds__(256) void k_mask(const int* __restrict__ T,
                                              int* __restrict__ colnz) {
  int r0 = blockIdx.x * 16;
  int a0 = 0, a1 = 0;
  for (int r = 0; r < 16; ++r) {
    const int* row = T + (size_t)(r0 + r) * NC;
    a0 |= row[threadIdx.x];
    a1 |= row[threadIdx.x + 256];
  }
  if (a0) atomicOr(colnz + threadIdx.x, 1);
  if (a1) atomicOr(colnz + threadIdx.x + 256, 1);
}

__global__ __launch_bounds__(512) void k_scan(const int* __restrict__ colnz,
                                              int* __restrict__ pos) {
  __shared__ int s[NC];
  int t = threadIdx.x;
  int f = colnz[t] ? 1 : 0;
  s[t] = f;
  __syncthreads();
  for (int o = 1; o < NC; o <<= 1) {
    int add = (t >= o) ? s[t - o] : 0;
    __syncthreads();
    s[t] += add;
    __syncthreads();
  }
  pos[t] = s[t] - f;
}

// ---------- fused: X-normalize + split-bf16 GEMM + softmax + S + loss partials ---
// grid = NB/16 = 256 blocks, 512 threads = 8 waves. Block tile: 16 rows x 512 cols.
// A (16 rows, K=256, hi+lo) built in registers from X; B read fragment-ordered
// (wave-contiguous 1KB bursts) from L2. D lives only in LDS.
__global__ __launch_bounds__(512) void k_fused(const float* __restrict__ X,
                                               const int* __restrict__ T,
                                               const ushort* __restrict__ Bh,
                                               const ushort* __restrict__ Bl,
                                               const float* __restrict__ t3,
                                               const int* __restrict__ colnz,
                                               const int* __restrict__ pos,
                                               float* __restrict__ Sout,
                                               float* __restrict__ blklog,
                                               int* __restrict__ blkcnt,
                                               int Csel, int ident) {
  // 514-word row stride: MFMA->LDS writes land 2-way (free), softmax reads clean.
  __shared__ float Dls[16][514];
  __shared__ float sl16[16];
  __shared__ int sc16[16];
  int tid = threadIdx.x;
  int lane = tid & 63, w = tid >> 6;
  int lr = lane & 15, kq = lane >> 4;
  int r0 = blockIdx.x * 16;

  // ---- build A fragments in registers ----
  // lane covers row (r0+lr), k-slices k = 32c + 8kq + j (j=0..7, c=0..7)
  float xv[4][8];
  float rsum = 0.f;
  const float* xrow = X + (size_t)(r0 + lr) * NF + 8 * kq;
  #pragma unroll
  for (int c = 0; c < 4; ++c) {
    float4 u0 = *(const float4*)(xrow + 32 * c);
    float4 u1 = *(const float4*)(xrow + 32 * c + 4);
    xv[c][0] = u0.x; xv[c][1] = u0.y; xv[c][2] = u0.z; xv[c][3] = u0.w;
    xv[c][4] = u1.x; xv[c][5] = u1.y; xv[c][6] = u1.z; xv[c][7] = u1.w;
    #pragma unroll
    for (int j = 0; j < 8; ++j) rsum = fmaf(xv[c][j], xv[c][j], rsum);
  }
  rsum += __shfl_xor(rsum, 16, 64);
  rsum += __shfl_xor(rsum, 32, 64);
  float rn = 1.0f / fmaxf(sqrtf(rsum), 1e-12f);

  bf16x8 Afh[8], Afl[8];
  #pragma unroll
  for (int c = 0; c < 4; ++c) {
    #pragma unroll
    for (int j = 0; j < 8; ++j) {
      float xn = xv[c][j] * rn;
      short h, l;
      splitbf(xn * xn, h, l);
      Afh[c][j] = h; Afl[c][j] = l;
      splitbf(xn, h, l);
      Afh[c + 4][j] = h; Afl[c + 4][j] = l;
    }
  }

  // ---- prefetch epilogue T rows (HBM latency hides under MFMA loop) ----
  int tf0[8], tf1[8];
  {
    const int* Trow0 = T + (size_t)(r0 + 2 * w) * NC;
    const int* Trow1 = T + (size_t)(r0 + 2 * w + 1) * NC;
    #pragma unroll
    for (int j = 0; j < 8; ++j) {
      tf0[j] = Trow0[lane + 64 * j];
      tf1[j] = Trow1[lane + 64 * j];
    }
  }

  // ---- MFMA main loop: 3-product split-bf16 over col tiles t=0..3 ----
  // B fragment-ordered: load for (ct,k8) is lane-contiguous (1KB/wave burst).
  f32x4 acc[4] = {};
  #pragma unroll
  for (int k8 = 0; k8 < 8; ++k8) {
    #pragma unroll
    for (int t = 0; t < 4; ++t) {
      size_t off = (((size_t)(w * 4 + t) * 8 + k8) * 64 + lane) * 8;
      bf16x8 bh = *(const bf16x8*)(Bh + off);
      bf16x8 bl = *(const bf16x8*)(Bl + off);
      acc[t] = __builtin_amdgcn_mfma_f32_16x16x32_bf16(Afh[k8], bh, acc[t], 0, 0, 0);
      acc[t] = __builtin_amdgcn_mfma_f32_16x16x32_bf16(Afl[k8], bh, acc[t], 0, 0, 0);
      acc[t] = __builtin_amdgcn_mfma_f32_16x16x32_bf16(Afh[k8], bl, acc[t], 0, 0, 0);
    }
  }

  // ---- D tile -> LDS (add t3); C/D layout: col=lane&15, row=4*kq+i ----
  int n0 = w * 64;
  #pragma unroll
  for (int t = 0; t < 4; ++t) {
    int c = n0 + 16 * t + lr;
    float tt = t3[c];
    #pragma unroll
    for (int i = 0; i < 4; ++i) Dls[4 * kq + i][c] = acc[t][i] + tt;
  }
  __syncthreads();

  // ---- per-row softmax + S + loss terms; wave w handles rows 2w, 2w+1 ----
  #pragma unroll
  for (int rr = 0; rr < 2; ++rr) {
    int r = 2 * w + rr;
    const int* tf = rr ? tf1 : tf0;
    float d[8];
    #pragma unroll
    for (int j = 0; j < 8; ++j) d[j] = Dls[r][lane + 64 * j];
    float dmin = d[0];
    #pragma unroll
    for (int j = 1; j < 8; ++j) dmin = fminf(dmin, d[j]);
    #pragma unroll
    for (int o = 1; o < 64; o <<= 1) dmin = fminf(dmin, __shfl_xor(dmin, o, 64));
    float Z = 0.f, Ps = 0.f;
    #pragma unroll
    for (int j = 0; j < 8; ++j) {
      float p = __expf(TAUc * (dmin - d[j]));
      Z += p;
      if (tf[j]) Ps += p;
    }
    #pragma unroll
    for (int o = 1; o < 64; o <<= 1) { Z += __shfl_xor(Z, o, 64); Ps += __shfl_xor(Ps, o, 64); }
    float* srow = Sout + (size_t)(r0 + r) * Csel;
    if (ident) {
      #pragma unroll
      for (int j = 0; j < 8; ++j)
        srow[lane + 64 * j] = tf[j] ? 1.0f : __expf(-ALPHAc * d[j]);
    } else {
      #pragma unroll
      for (int j = 0; j < 8; ++j) {
        int c = lane + 64 * j;
        if (colnz[c]) srow[pos[c]] = tf[j] ? 1.0f : __expf(-ALPHAc * d[j]);
      }
    }
    if (lane == 0) {
      float Psum = Ps / Z;
      sl16[r] = (Psum > 0.f) ? logf(Psum) : 0.f;
      sc16[r] = (Psum > 0.f) ? 1 : 0;
    }
  }
  __syncthreads();
  if (tid == 0) {
    float s = 0.f; int c = 0;
    #pragma unroll
    for (int r = 0; r < 16; ++r) { s += sl16[r]; c += sc16[r]; }
    blklog[blockIdx.x] = s;
    blkcnt[blockIdx.x] = c;
  }
}

// ---------- finalize loss (reads NB/16 = 256 partials; kernel boundary = fence) --
__global__ __launch_bounds__(256) void k_fin(const float* __restrict__ blklog,
                                             const int* __restrict__ blkcnt,
                                             float* __restrict__ out) {
  __shared__ float sl[256];
  __shared__ int sc[256];
  int t = threadIdx.x;
  sl[t] = blklog[t];
  sc[t] = blkcnt[t];
  __syncthreads();
  for (int o = 128; o > 0; o >>= 1) {
    if (t < o) { sl[t] += sl[t + o]; sc[t] += sc[t + o]; }
    __syncthreads();
  }
  if (t == 0) out[0] = -sl[0] / fmaxf((float)sc[0], 1.0f);
}

extern "C" void kernel_launch(void* const* d_in, const int* in_sizes, int n_in,
                              void* d_out, int out_size, void* d_ws, size_t ws_size,
                              hipStream_t stream) {
  const float* X     = (const float*)d_in[0];
  const int*   T     = (const int*)d_in[1];
  const float* means = (const float*)d_in[2];
  const float* logv  = (const float*)d_in[3];
  float* out = (float*)d_out;
  char* ws = (char*)d_ws;

  ushort* Bh      = (ushort*)(ws);                  // 256 KB
  ushort* Bl      = (ushort*)(ws + 262144);         // 256 KB
  float*  t3      = (float*) (ws + 524288);         // 2 KB
  float*  blklog  = (float*) (ws + 526336);         // 1 KB
  int*    blkcnt  = (int*)   (ws + 527360);         // 1 KB
  int*    colnz   = (int*)   (ws + 528384);         // 2 KB
  int*    pos     = (int*)   (ws + 530432);         // 2 KB

  int Csel = (out_size - 1) / NB;
  int ident = (Csel == NC);   // Csel==NC forces all-ones mask (pos = identity)

  k_prepB<<<NC, NF, 0, stream>>>(means, logv, Bh, Bl, t3);
  if (!ident) {
    k_zero<<<1, NC, 0, stream>>>(colnz);
    k_mask<<<NB / 16, 256, 0, stream>>>(T, colnz);
    k_scan<<<1, NC, 0, stream>>>(colnz, pos);
  }
  k_fused<<<NB / 16, 512, 0, stream>>>(X, T, Bh, Bl, t3, colnz, pos,
                                       out + 1, blklog, blkcnt, Csel, ident);
  k_fin<<<1, 256, 0, stream>>>(blklog, blkcnt, out);
}

// Round 7
// 23.754 us; speedup vs baseline: 1.5205x; 1.0742x over previous
//
#include <hip/hip_runtime.h>
#include <hip/hip_bf16.h>
#include <math.h>

#define NB 4096
#define NC 512
#define NF 128
#define NK 256           // GEMM K = 2*F  (k<128: xn^2 . iv ; k>=128: xn . -2*mu*iv)
#define TAUc 32.0f
#define ALPHAc 0.9f

typedef __attribute__((ext_vector_type(8))) short bf16x8;
typedef __attribute__((ext_vector_type(4))) float f32x4;
typedef __attribute__((address_space(1))) const unsigned int gu32;
typedef __attribute__((address_space(3))) unsigned int lu32;

// Truncation-based bf16 hi/lo split: hi = trunc16(x), lo = trunc16(x - hi).
__device__ inline void splitbf(float x, short& hi, short& lo) {
  unsigned u = __float_as_uint(x);
  hi = (short)(u >> 16);
  float l = x - __uint_as_float(u & 0xFFFF0000u);
  lo = (short)(__float_as_uint(l) >> 16);
}

// ---------- prepB: mu_n, iv=exp(-clip(lv)); B = [iv, -2*mu_n*iv] hi/lo; t3 -------
// B stored PRE-SWIZZLED in MFMA fragment order: elem = ((ct*8 + k8)*64 + lane)*8 + j
// (col = ct*16 + lr, k = 32*k8 + 8*kq + j, lane = kq*16 + lr)
__global__ __launch_bounds__(128) void k_prepB(const float* __restrict__ means,
                                               const float* __restrict__ logv,
                                               ushort* __restrict__ Bh,
                                               ushort* __restrict__ Bl,
                                               float* __restrict__ t3) {
  __shared__ float p2[2];
  __shared__ float q2[2];
  int c = blockIdx.x, f = threadIdx.x;
  float mu = means[(size_t)c * NF + f];
  float lv = fminf(fmaxf(logv[(size_t)c * NF + f], 0.f), 6.f);
  float iv = __expf(-lv);
  float s = mu * mu;
  #pragma unroll
  for (int o = 1; o < 64; o <<= 1) s += __shfl_xor(s, o, 64);
  if ((f & 63) == 0) p2[f >> 6] = s;
  __syncthreads();
  float mun = mu / fmaxf(sqrtf(p2[0] + p2[1]), 1e-12f);

  int ct = c >> 4, lr = c & 15;
  auto swadr = [&](int k) {
    return (size_t)(ct * 8 + (k >> 5)) * 512 + ((k >> 3) & 3) * 128 + lr * 8 + (k & 7);
  };
  short h, l;
  splitbf(iv, h, l);
  size_t a1 = swadr(f);
  Bh[a1] = (ushort)h; Bl[a1] = (ushort)l;
  splitbf(-2.f * mun * iv, h, l);
  size_t a2 = swadr(f + NF);
  Bh[a2] = (ushort)h; Bl[a2] = (ushort)l;

  float t = mun * mun * iv;
  #pragma unroll
  for (int o = 1; o < 64; o <<= 1) t += __shfl_xor(t, o, 64);
  if ((f & 63) == 0) q2[f >> 6] = t;
  __syncthreads();
  if (f == 0) t3[c] = q2[0] + q2[1];
}

// ---------- fallback-only mask machinery (not launched when Csel==NC) ------------
__global__ __launch_bounds__(512) void k_zero(int* __restrict__ colnz) {
  colnz[threadIdx.x] = 0;
}

__global__ __launch_bounds__(256) void k_mask(const int* __restrict__ T,
                                              int* __restrict__ colnz) {
  int r0 = blockIdx.x * 16;
  int a0 = 0, a1 = 0;
  for (int r = 0; r < 16; ++r) {
    const int* row = T + (size_t)(r0 + r) * NC;
    a0 |= row[threadIdx.x];
    a1 |= row[threadIdx.x + 256];
  }
  if (a0) atomicOr(colnz + threadIdx.x, 1);
  if (a1) atomicOr(colnz + threadIdx.x + 256, 1);
}

__global__ __launch_bounds__(512) void k_scan(const int* __restrict__ colnz,
                                              int* __restrict__ pos) {
  __shared__ int s[NC];
  int t = threadIdx.x;
  int f = colnz[t] ? 1 : 0;
  s[t] = f;
  __syncthreads();
  for (int o = 1; o < NC; o <<= 1) {
    int add = (t >= o) ? s[t - o] : 0;
    __syncthreads();
    s[t] += add;
    __syncthreads();
  }
  pos[t] = s[t] - f;
}

// ---------- fused: X-normalize + split-bf16 GEMM + softmax + S + loss partials ---
// grid = NB/16 = 256 blocks, 512 threads = 8 waves. Block tile: 16 rows x 512 cols.
// B streamed global->LDS via global_load_lds (wave-private 16KB double-buffer,
// counted vmcnt(8), no barriers in the K-loop). LDS staging region (128 KB) is
// reused for the D-tile after the loop (barrier-separated lifetimes).
__global__ __launch_bounds__(512) void k_fused(const float* __restrict__ X,
                                               const int* __restrict__ T,
                                               const ushort* __restrict__ Bh,
                                               const ushort* __restrict__ Bl,
                                               const float* __restrict__ t3,
                                               const int* __restrict__ colnz,
                                               const int* __restrict__ pos,
                                               float* __restrict__ Sout,
                                               float* __restrict__ blklog,
                                               int* __restrict__ blkcnt,
                                               int Csel, int ident) {
  __shared__ __align__(16) unsigned char smraw[131072];   // 128 KB B-stage / D-tile
  __shared__ float sl16[16];
  __shared__ int sc16[16];
  int tid = threadIdx.x;
  int lane = tid & 63, w = tid >> 6;
  int lr = lane & 15, kq = lane >> 4;
  int r0 = blockIdx.x * 16;

  // ---- issue first B chunk immediately (overlaps the whole A-build) ----
  auto stage = [&](int p) {
    int par = p & 1;
    #pragma unroll
    for (int t = 0; t < 4; ++t) {
      size_t goff = (((size_t)(w * 4 + t) * 8 + p) * 64 + lane) * 8;
      unsigned ldso = (unsigned)(w * 16384 + par * 8192 + t * 2048);
      __builtin_amdgcn_global_load_lds((gu32*)(Bh + goff), (lu32*)(smraw + ldso), 16, 0, 0);
      __builtin_amdgcn_global_load_lds((gu32*)(Bl + goff), (lu32*)(smraw + ldso + 1024), 16, 0, 0);
    }
  };
  stage(0);

  // ---- build A fragments in registers ----
  // lane covers row (r0+lr), k-slices k = 32c + 8kq + j (j=0..7, c=0..7)
  float xv[4][8];
  float rsum = 0.f;
  const float* xrow = X + (size_t)(r0 + lr) * NF + 8 * kq;
  #pragma unroll
  for (int c = 0; c < 4; ++c) {
    float4 u0 = *(const float4*)(xrow + 32 * c);
    float4 u1 = *(const float4*)(xrow + 32 * c + 4);
    xv[c][0] = u0.x; xv[c][1] = u0.y; xv[c][2] = u0.z; xv[c][3] = u0.w;
    xv[c][4] = u1.x; xv[c][5] = u1.y; xv[c][6] = u1.z; xv[c][7] = u1.w;
    #pragma unroll
    for (int j = 0; j < 8; ++j) rsum = fmaf(xv[c][j], xv[c][j], rsum);
  }
  rsum += __shfl_xor(rsum, 16, 64);
  rsum += __shfl_xor(rsum, 32, 64);
  float rn = 1.0f / fmaxf(sqrtf(rsum), 1e-12f);

  bf16x8 Afh[8], Afl[8];
  #pragma unroll
  for (int c = 0; c < 4; ++c) {
    #pragma unroll
    for (int j = 0; j < 8; ++j) {
      float xn = xv[c][j] * rn;
      short h, l;
      splitbf(xn * xn, h, l);
      Afh[c][j] = h; Afl[c][j] = l;
      splitbf(xn, h, l);
      Afh[c + 4][j] = h; Afl[c + 4][j] = l;
    }
  }

  // ---- prefetch epilogue T rows (HBM latency hides under MFMA loop) ----
  int tf0[8], tf1[8];
  {
    const int* Trow0 = T + (size_t)(r0 + 2 * w) * NC;
    const int* Trow1 = T + (size_t)(r0 + 2 * w + 1) * NC;
    #pragma unroll
    for (int j = 0; j < 8; ++j) {
      tf0[j] = Trow0[lane + 64 * j];
      tf1[j] = Trow1[lane + 64 * j];
    }
  }

  // ---- MFMA main loop: 3-product split-bf16; B from wave-private LDS ----
  const bf16x8* wstage = (const bf16x8*)(smraw + w * 16384);
  f32x4 acc[4] = {};
  #pragma unroll
  for (int k8 = 0; k8 < 8; ++k8) {
    if (k8 < 7) {
      stage(k8 + 1);
      // 8 younger VMEM ops (next chunk) may remain outstanding; chunk k8 is done.
      asm volatile("s_waitcnt vmcnt(8)" ::: "memory");
    } else {
      asm volatile("s_waitcnt vmcnt(0)" ::: "memory");
    }
    int par = k8 & 1;
    #pragma unroll
    for (int t = 0; t < 4; ++t) {
      bf16x8 bh = wstage[(par * 8 + t * 2) * 64 + lane];
      bf16x8 bl = wstage[(par * 8 + t * 2 + 1) * 64 + lane];
      acc[t] = __builtin_amdgcn_mfma_f32_16x16x32_bf16(Afh[k8], bh, acc[t], 0, 0, 0);
      acc[t] = __builtin_amdgcn_mfma_f32_16x16x32_bf16(Afl[k8], bh, acc[t], 0, 0, 0);
      acc[t] = __builtin_amdgcn_mfma_f32_16x16x32_bf16(Afh[k8], bl, acc[t], 0, 0, 0);
    }
  }
  __syncthreads();   // all waves done with B-stage; safe to overwrite with D-tile

  // ---- D tile -> LDS (add t3); C/D layout: col=lane&15, row=4*kq+i ----
  float (*Dls)[514] = (float (*)[514])smraw;   // 16*514*4 = 32.9 KB < 128 KB
  int n0 = w * 64;
  #pragma unroll
  for (int t = 0; t < 4; ++t) {
    int c = n0 + 16 * t + lr;
    float tt = t3[c];
    #pragma unroll
    for (int i = 0; i < 4; ++i) Dls[4 * kq + i][c] = acc[t][i] + tt;
  }
  __syncthreads();

  // ---- per-row softmax + S + loss terms; wave w handles rows 2w, 2w+1 ----
  #pragma unroll
  for (int rr = 0; rr < 2; ++rr) {
    int r = 2 * w + rr;
    const int* tf = rr ? tf1 : tf0;
    float d[8];
    #pragma unroll
    for (int j = 0; j < 8; ++j) d[j] = Dls[r][lane + 64 * j];
    float dmin = d[0];
    #pragma unroll
    for (int j = 1; j < 8; ++j) dmin = fminf(dmin, d[j]);
    #pragma unroll
    for (int o = 1; o < 64; o <<= 1) dmin = fminf(dmin, __shfl_xor(dmin, o, 64));
    float Z = 0.f, Ps = 0.f;
    #pragma unroll
    for (int j = 0; j < 8; ++j) {
      float p = __expf(TAUc * (dmin - d[j]));
      Z += p;
      if (tf[j]) Ps += p;
    }
    #pragma unroll
    for (int o = 1; o < 64; o <<= 1) { Z += __shfl_xor(Z, o, 64); Ps += __shfl_xor(Ps, o, 64); }
    float* srow = Sout + (size_t)(r0 + r) * Csel;
    if (ident) {
      #pragma unroll
      for (int j = 0; j < 8; ++j)
        srow[lane + 64 * j] = tf[j] ? 1.0f : __expf(-ALPHAc * d[j]);
    } else {
      #pragma unroll
      for (int j = 0; j < 8; ++j) {
        int c = lane + 64 * j;
        if (colnz[c]) srow[pos[c]] = tf[j] ? 1.0f : __expf(-ALPHAc * d[j]);
      }
    }
    if (lane == 0) {
      float Psum = Ps / Z;
      sl16[r] = (Psum > 0.f) ? logf(Psum) : 0.f;
      sc16[r] = (Psum > 0.f) ? 1 : 0;
    }
  }
  __syncthreads();
  if (tid == 0) {
    float s = 0.f; int c = 0;
    #pragma unroll
    for (int r = 0; r < 16; ++r) { s += sl16[r]; c += sc16[r]; }
    blklog[blockIdx.x] = s;
    blkcnt[blockIdx.x] = c;
  }
}

// ---------- finalize loss (reads NB/16 = 256 partials; kernel boundary = fence) --
__global__ __launch_bounds__(256) void k_fin(const float* __restrict__ blklog,
                                             const int* __restrict__ blkcnt,
                                             float* __restrict__ out) {
  __shared__ float sl[256];
  __shared__ int sc[256];
  int t = threadIdx.x;
  sl[t] = blklog[t];
  sc[t] = blkcnt[t];
  __syncthreads();
  for (int o = 128; o > 0; o >>= 1) {
    if (t < o) { sl[t] += sl[t + o]; sc[t] += sc[t + o]; }
    __syncthreads();
  }
  if (t == 0) out[0] = -sl[0] / fmaxf((float)sc[0], 1.0f);
}

extern "C" void kernel_launch(void* const* d_in, const int* in_sizes, int n_in,
                              void* d_out, int out_size, void* d_ws, size_t ws_size,
                              hipStream_t stream) {
  const float* X     = (const float*)d_in[0];
  const int*   T     = (const int*)d_in[1];
  const float* means = (const float*)d_in[2];
  const float* logv  = (const float*)d_in[3];
  float* out = (float*)d_out;
  char* ws = (char*)d_ws;

  ushort* Bh      = (ushort*)(ws);                  // 256 KB
  ushort* Bl      = (ushort*)(ws + 262144);         // 256 KB
  float*  t3      = (float*) (ws + 524288);         // 2 KB
  float*  blklog  = (float*) (ws + 526336);         // 1 KB
  int*    blkcnt  = (int*)   (ws + 527360);         // 1 KB
  int*    colnz   = (int*)   (ws + 528384);         // 2 KB
  int*    pos     = (int*)   (ws + 530432);         // 2 KB

  int Csel = (out_size - 1) / NB;
  int ident = (Csel == NC);   // Csel==NC forces all-ones mask (pos = identity)

  k_prepB<<<NC, NF, 0, stream>>>(means, logv, Bh, Bl, t3);
  if (!ident) {
    k_zero<<<1, NC, 0, stream>>>(colnz);
    k_mask<<<NB / 16, 256, 0, stream>>>(T, colnz);
    k_scan<<<1, NC, 0, stream>>>(colnz, pos);
  }
  k_fused<<<NB / 16, 512, 0, stream>>>(X, T, Bh, Bl, t3, colnz, pos,
                                       out + 1, blklog, blkcnt, Csel, ident);
  k_fin<<<1, 256, 0, stream>>>(blklog, blkcnt, out);
}